// Round 1
// baseline (58582.294 us; speedup 1.0000x reference)
//
#include <hip/hip_runtime.h>
#include <hip/hip_cooperative_groups.h>
#include <math.h>

namespace cg = cooperative_groups;

// Problem constants
#define T_STEPS 256
#define BATCH   8
#define HID     1024
#define KTWO    2048   // I + H
#define NHEAD   16
#define DHEAD   64

// ws float offsets
#define OFF_HX  0
#define OFF_CX  8192
#define OFF_H0  16384
#define OFF_CTX 24576
#define OFF_Z   32768           // [4][8][1024]
#define OFF_KB  65536           // [256][8][1024]
#define OFF_VB  (65536 + 2097152)

__global__ __launch_bounds__(256, 1)
void qlstm_kernel(const float* __restrict__ x,  const float* __restrict__ Wg,
                  const float* __restrict__ bg, const float* __restrict__ lng,
                  const float* __restrict__ lnb,const float* __restrict__ Wq,
                  const float* __restrict__ Wk, const float* __restrict__ Wv,
                  const float* __restrict__ bq, const float* __restrict__ bk,
                  const float* __restrict__ bv, const float* __restrict__ Wo,
                  const float* __restrict__ bo, float* __restrict__ out,
                  float* __restrict__ ws)
{
    cg::grid_group grid = cg::this_grid();
    const int blk = blockIdx.x, tid = threadIdx.x;

    float* hx  = ws + OFF_HX;
    float* cx  = ws + OFF_CX;
    float* h0  = ws + OFF_H0;
    float* ctx = ws + OFF_CTX;
    float* z   = ws + OFF_Z;
    float* Kb  = ws + OFF_KB;
    float* Vb  = ws + OFF_VB;

    __shared__ float sm[336];  // [0..63] q, [64..319] p, [320..327] red, [328..335] LN stats

    // init hx, cx to zero (they are contiguous: ws[0 .. 16384))
    { const int idx = blk * 256 + tid; if (idx < 16384) ws[idx] = 0.f; }
    grid.sync();

    for (int t = 0; t < T_STEPS; ++t) {
        // ---------------- Phase A: z-GEMM (blocks 0..127) + K/V proj (128..255) ----
        if (blk < 128) {
            const int lr = tid >> 3, ks = tid & 7;          // 32 rows x 8 k-splits
            const int r  = blk * 32 + lr;                   // 0..4095
            const int g  = r >> 10, h = r & 1023;
            const float* wrow = Wg + (size_t)r * KTWO;
            const float* xt   = x + (size_t)t * (BATCH * 1024);
            float acc[8] = {0.f,0.f,0.f,0.f,0.f,0.f,0.f,0.f};
            for (int i = 0; i < 64; ++i) {
                const int k = i * 32 + ks * 4;              // covers [0,2048) in 4s
                const float4 w4 = *(const float4*)(wrow + k);
                const float* src = (k < 1024) ? (xt + k) : (hx + (k - 1024));
                #pragma unroll
                for (int b = 0; b < 8; ++b) {
                    const float4 c4 = *(const float4*)(src + b * 1024);
                    acc[b] += w4.x*c4.x + w4.y*c4.y + w4.z*c4.z + w4.w*c4.w;
                }
            }
            #pragma unroll
            for (int o = 1; o < 8; o <<= 1)
                #pragma unroll
                for (int b = 0; b < 8; ++b) acc[b] += __shfl_xor(acc[b], o);
            if (ks == 0) {
                const float bias = bg[g * 1024 + h];
                #pragma unroll
                for (int b = 0; b < 8; ++b)
                    z[(size_t)(g * 8 + b) * 1024 + h] = acc[b] + bias;
            }
        } else if (t > 0) {
            const int bx = blk - 128;
            const int lr = tid >> 4, ks = tid & 15;         // 16 rows x 16 k-splits
            const int rv = bx * 16 + lr;                    // 0..2047
            const int mat = rv >> 10, h = rv & 1023;
            const float* wrow = (mat ? Wv : Wk) + (size_t)h * 1024;
            float acc[8] = {0.f,0.f,0.f,0.f,0.f,0.f,0.f,0.f};
            for (int i = 0; i < 16; ++i) {
                const int k = i * 64 + ks * 4;              // covers [0,1024)
                const float4 w4 = *(const float4*)(wrow + k);
                #pragma unroll
                for (int b = 0; b < 8; ++b) {
                    const float4 c4 = *(const float4*)(hx + b * 1024 + k);
                    acc[b] += w4.x*c4.x + w4.y*c4.y + w4.z*c4.z + w4.w*c4.w;
                }
            }
            #pragma unroll
            for (int o = 1; o < 16; o <<= 1)
                #pragma unroll
                for (int b = 0; b < 8; ++b) acc[b] += __shfl_xor(acc[b], o);
            if (ks == 0) {
                const float bias = (mat ? bv : bk)[h];
                float* dst = mat ? Vb : Kb;
                #pragma unroll
                for (int b = 0; b < 8; ++b)
                    dst[((size_t)(t - 1) * 8 + b) * 1024 + h] = acc[b] + bias;
            }
        }
        grid.sync();

        // ---------------- Phase B: LN + gates + cell update (blocks 0..7) ----------
        if (blk < 8) {
            const int b = blk, wv = tid >> 6, lane = tid & 63;  // wave per gate
            const float* zr = z + (size_t)(wv * 8 + b) * 1024;
            float s = 0.f, q = 0.f;
            for (int h = lane; h < 1024; h += 64) { const float v = zr[h]; s += v; q += v * v; }
            #pragma unroll
            for (int o = 1; o < 64; o <<= 1) { s += __shfl_xor(s, o); q += __shfl_xor(q, o); }
            if (lane == 0) { sm[328 + wv * 2] = s; sm[329 + wv * 2] = q; }
            __syncthreads();
            float mean[4], rstd[4];
            #pragma unroll
            for (int g2 = 0; g2 < 4; ++g2) {
                const float m = sm[328 + g2 * 2] * (1.f / 1024.f);
                mean[g2] = m;
                rstd[g2] = rsqrtf(sm[329 + g2 * 2] * (1.f / 1024.f) - m * m + 1e-5f);
            }
            for (int h = tid; h < 1024; h += 256) {
                float zv[4];
                #pragma unroll
                for (int g2 = 0; g2 < 4; ++g2) {
                    const float v = z[(size_t)(g2 * 8 + b) * 1024 + h];
                    zv[g2] = (v - mean[g2]) * rstd[g2] * lng[g2 * 1024 + h] + lnb[g2 * 1024 + h];
                }
                const float f  = 1.f / (1.f + expf(-zv[0]));
                const float ii = 1.f / (1.f + expf(-zv[1]));
                const float gg = tanhf(zv[2]);
                const float oo = 1.f / (1.f + expf(-zv[3]));
                const float c  = f * cx[b * 1024 + h] + ii * gg;
                cx[b * 1024 + h] = c;
                h0[b * 1024 + h] = oo * tanhf(c);
            }
        }
        grid.sync();

        // ---------------- Phase C: q-proj + attention (blocks 0..127, t>0) ---------
        if (blk < 128 && t > 0) {
            const int b = blk >> 4, nh = blk & 15;
            {   // q projection: 64 rows, K=1024; thread = (dh, ks4)
                const int dh = tid >> 2, ks = tid & 3;
                const float* wrow = Wq + (size_t)(nh * 64 + dh) * 1024;
                const float* hb = h0 + b * 1024;
                float acc = 0.f;
                for (int i = 0; i < 64; ++i) {
                    const int k = i * 16 + ks * 4;
                    const float4 w4 = *(const float4*)(wrow + k);
                    const float4 c4 = *(const float4*)(hb + k);
                    acc += w4.x*c4.x + w4.y*c4.y + w4.z*c4.z + w4.w*c4.w;
                }
                acc += __shfl_xor(acc, 1); acc += __shfl_xor(acc, 2);
                if (ks == 0) sm[dh] = (acc + bq[nh * 64 + dh]) * 0.125f;  // 1/sqrt(64)
            }
            __syncthreads();
            // scores: one thread per past position s = tid
            float sc = -3.0e38f;
            if (tid < t) {
                const float* kr = Kb + ((size_t)tid * 8 + b) * 1024 + nh * 64;
                float d = 0.f;
                #pragma unroll
                for (int j = 0; j < 64; j += 4) {
                    const float4 k4 = *(const float4*)(kr + j);
                    d += k4.x*sm[j] + k4.y*sm[j+1] + k4.z*sm[j+2] + k4.w*sm[j+3];
                }
                sc = d;
            }
            float m = sc;
            #pragma unroll
            for (int o = 1; o < 64; o <<= 1) m = fmaxf(m, __shfl_xor(m, o));
            if ((tid & 63) == 0) sm[320 + (tid >> 6)] = m;
            __syncthreads();
            m = fmaxf(fmaxf(sm[320], sm[321]), fmaxf(sm[322], sm[323]));
            const float p = (tid < t) ? expf(sc - m) : 0.f;
            sm[64 + tid] = p;
            float ssum = p;
            #pragma unroll
            for (int o = 1; o < 64; o <<= 1) ssum += __shfl_xor(ssum, o);
            if ((tid & 63) == 0) sm[324 + (tid >> 6)] = ssum;
            __syncthreads();
            const float inv = 1.f / (sm[324] + sm[325] + sm[326] + sm[327]);
            // ctx: thread = (dh, ss4)
            const int dh = tid >> 2, ss = tid & 3;
            float ca = 0.f;
            for (int s2 = ss; s2 < t; s2 += 4)
                ca += sm[64 + s2] * Vb[((size_t)s2 * 8 + b) * 1024 + nh * 64 + dh];
            ca += __shfl_xor(ca, 1); ca += __shfl_xor(ca, 2);
            if (ss == 0) ctx[b * 1024 + nh * 64 + dh] = ca * inv;
        }
        grid.sync();

        // ---------------- Phase D: out-proj + hx update + emit (blocks 0..31) ------
        if (blk < 32) {
            const int lr = tid >> 3, ks = tid & 7;          // 32 rows x 8 k-splits
            const int r  = blk * 32 + lr;                   // 0..1023
            const float* wrow = Wo + (size_t)r * 1024;
            float acc[8] = {0.f,0.f,0.f,0.f,0.f,0.f,0.f,0.f};
            for (int i = 0; i < 32; ++i) {
                const int k = i * 32 + ks * 4;
                const float4 w4 = *(const float4*)(wrow + k);
                #pragma unroll
                for (int b = 0; b < 8; ++b) {
                    const float4 c4 = *(const float4*)(ctx + b * 1024 + k);
                    acc[b] += w4.x*c4.x + w4.y*c4.y + w4.z*c4.z + w4.w*c4.w;
                }
            }
            #pragma unroll
            for (int o = 1; o < 8; o <<= 1)
                #pragma unroll
                for (int b = 0; b < 8; ++b) acc[b] += __shfl_xor(acc[b], o);
            if (ks == 0) {
                #pragma unroll
                for (int b = 0; b < 8; ++b) {
                    float v = h0[b * 1024 + r];
                    if (t > 0) v += acc[b] + bo[r];
                    hx[b * 1024 + r] = v;
                    out[(size_t)t * 8192 + b * 1024 + r] = v;
                }
            }
        }
        grid.sync();
    }

    // epilogue: final hx, cx
    if (blk < 8) {
        for (int h = tid; h < 1024; h += 256)
            out[2097152 + blk * 1024 + h] = hx[blk * 1024 + h];
    } else if (blk < 16) {
        const int b = blk - 8;
        for (int h = tid; h < 1024; h += 256)
            out[2097152 + 8192 + b * 1024 + h] = cx[b * 1024 + h];
    }
}

extern "C" void kernel_launch(void* const* d_in, const int* in_sizes, int n_in,
                              void* d_out, int out_size, void* d_ws, size_t ws_size,
                              hipStream_t stream) {
    const float* x   = (const float*)d_in[0];
    const float* Wg  = (const float*)d_in[1];
    const float* bg  = (const float*)d_in[2];
    const float* lng = (const float*)d_in[3];
    const float* lnb = (const float*)d_in[4];
    const float* Wq  = (const float*)d_in[5];
    const float* Wk  = (const float*)d_in[6];
    const float* Wv  = (const float*)d_in[7];
    const float* bq  = (const float*)d_in[8];
    const float* bk  = (const float*)d_in[9];
    const float* bv  = (const float*)d_in[10];
    const float* Wo  = (const float*)d_in[11];
    const float* bo  = (const float*)d_in[12];
    float* out = (float*)d_out;
    float* ws  = (float*)d_ws;

    void* args[] = { &x, &Wg, &bg, &lng, &lnb, &Wq, &Wk, &Wv,
                     &bq, &bk, &bv, &Wo, &bo, &out, &ws };
    hipLaunchCooperativeKernel((void*)qlstm_kernel, dim3(256), dim3(256),
                               args, 0, stream);
}